// Round 10
// baseline (682.173 us; speedup 1.0000x reference)
//
#include <hip/hip_runtime.h>
#include <hip/hip_fp16.h>
#include <cstdint>
#include <cstddef>

// ---------------------------------------------------------------------------
// GraphAutoencoder: 2 x [4-head GATConv(128->128) -> concat -> Linear(512->128) -> ReLU]
// N=50000, E=800000 (+N self-loops). fp32 in/out.
// GEMMs: fp16 MFMA (round-9 verified structure). Scores fused in head GEMM.
// Aggregate: alpha pre-pass (per-edge weight+src, per-node denom), then
// XCD-pinned column-slab gather (slab = blockIdx%8) for L2 locality.
// ---------------------------------------------------------------------------

#define FDIM   128
#define HEADS  4
#define HCAT   512

typedef unsigned short u16;
typedef __attribute__((ext_vector_type(4))) float f32x4;
typedef __attribute__((ext_vector_type(8))) _Float16 f16x8;

__device__ __forceinline__ u16 f2h_bits(float f) {
    _Float16 h = (_Float16)f;
    return *(u16*)&h;
}
__device__ __forceinline__ float h2f_bits(u16 b) {
    _Float16 h = *(_Float16*)&b;
    return (float)h;
}

// ---------------- edge dtype detection (int64 vs int32) ---------------------
__global__ void k_detect(const void* ei, int E, int N, int* flag) {
    if (threadIdx.x == 0 && blockIdx.x == 0) {
        const long long* p = (const long long*)ei;
        int bad = 0;
        int n = E < 64 ? E : 64;
        for (int i = 0; i < n; ++i) {
            long long v = p[i];
            if (v < 0 || v >= (long long)N) bad = 1;
        }
        *flag = bad;  // 1 => int32, 0 => int64
    }
}

__device__ __forceinline__ int edge_at(const void* ei, int is32, long long pos) {
    return is32 ? ((const int*)ei)[pos] : (int)(((const long long*)ei)[pos]);
}

__global__ void k_zero_i32(int* p, int n) {
    int i = blockIdx.x * blockDim.x + threadIdx.x;
    if (i < n) p[i] = 0;
}

__global__ void k_count(const void* ei, const int* flag, int E, int N, int* deg) {
    int e = blockIdx.x * blockDim.x + threadIdx.x;
    int Etot = E + N;
    if (e >= Etot) return;
    int is32 = *flag;
    int dst = (e < E) ? edge_at(ei, is32, (long long)E + e) : (e - E);
    atomicAdd(&deg[dst], 1);
}

// ---------------- multi-block exclusive scan --------------------------------
#define SCAN_BLOCKS 256
#define SCAN_TPB    256

__global__ __launch_bounds__(SCAN_TPB) void k_scan1(const int* __restrict__ deg,
                                                    int* __restrict__ bsum, int N) {
    __shared__ int sdata[SCAN_TPB];
    int b = blockIdx.x;
    int chunk = (N + SCAN_BLOCKS - 1) / SCAN_BLOCKS;
    int start = b * chunk;
    int end = start + chunk;
    if (start > N) start = N;
    if (end > N) end = N;
    int s = 0;
    for (int i = start + threadIdx.x; i < end; i += SCAN_TPB) s += deg[i];
    sdata[threadIdx.x] = s;
    __syncthreads();
    for (int o = SCAN_TPB / 2; o; o >>= 1) {
        if (threadIdx.x < o) sdata[threadIdx.x] += sdata[threadIdx.x + o];
        __syncthreads();
    }
    if (threadIdx.x == 0) bsum[b] = sdata[0];
}

__global__ __launch_bounds__(SCAN_BLOCKS) void k_scan2(const int* __restrict__ bsum,
                                                       int* __restrict__ bbase,
                                                       int* __restrict__ off_last) {
    __shared__ int sdata[SCAN_BLOCKS];
    int t = threadIdx.x;
    sdata[t] = bsum[t];
    __syncthreads();
    for (int o = 1; o < SCAN_BLOCKS; o <<= 1) {
        int v = (t >= o) ? sdata[t - o] : 0;
        __syncthreads();
        sdata[t] += v;
        __syncthreads();
    }
    bbase[t] = (t == 0) ? 0 : sdata[t - 1];
    if (t == SCAN_BLOCKS - 1) *off_last = sdata[t];
}

__global__ __launch_bounds__(SCAN_TPB) void k_scan3(const int* __restrict__ deg,
                                                    const int* __restrict__ bbase,
                                                    int* __restrict__ off,
                                                    int* __restrict__ cur, int N) {
    __shared__ int sdata[SCAN_TPB];
    int b = blockIdx.x;
    int chunk = (N + SCAN_BLOCKS - 1) / SCAN_BLOCKS;
    int start = b * chunk;
    int end = start + chunk;
    if (start > N) start = N;
    if (end > N) end = N;
    int base = bbase[b];
    for (int i0 = start; i0 < end; i0 += SCAN_TPB) {
        int i = i0 + threadIdx.x;
        int v = (i < end) ? deg[i] : 0;
        sdata[threadIdx.x] = v;
        __syncthreads();
        for (int o = 1; o < SCAN_TPB; o <<= 1) {
            int u = (threadIdx.x >= o) ? sdata[threadIdx.x - o] : 0;
            __syncthreads();
            sdata[threadIdx.x] += u;
            __syncthreads();
        }
        if (i < end) {
            int excl = base + sdata[threadIdx.x] - v;
            off[i] = excl;
            cur[i] = excl;
        }
        base += sdata[SCAN_TPB - 1];
        __syncthreads();
    }
}

__global__ void k_fill(const void* ei, const int* flag, int E, int N, int* cur, int* csr) {
    int e = blockIdx.x * blockDim.x + threadIdx.x;
    int Etot = E + N;
    if (e >= Etot) return;
    int is32 = *flag;
    int src, dst;
    if (e < E) {
        src = edge_at(ei, is32, e);
        dst = edge_at(ei, is32, (long long)E + e);
    } else {
        src = e - E;
        dst = e - E;
    }
    int pos = atomicAdd(&cur[dst], 1);
    csr[pos] = src;
}

// ---------------- operand prep ----------------------------------------------
// W [nblk][K][128] fp32 -> Wt hi/lo fp16 [nblk*128 cols][K] (transposed)
__global__ void k_splitw(const float* __restrict__ W, u16* __restrict__ hi,
                         u16* __restrict__ lo, int nblk, int K) {
    int idx = blockIdx.x * blockDim.x + threadIdx.x;
    int total = nblk * K * 128;
    if (idx >= total) return;
    int blk = idx / (K * 128);
    int rem = idx - blk * K * 128;
    int k = rem >> 7, col = rem & 127;
    float v = W[idx];
    _Float16 hh = (_Float16)v;
    _Float16 ll = (_Float16)(v - (float)hh);
    size_t o = (size_t)blk * 128 * K + (size_t)col * K + k;
    hi[o] = *(u16*)&hh;
    lo[o] = *(u16*)&ll;
}

__global__ void k_cvt_f16(const float* __restrict__ X, u16* __restrict__ out, int n) {
    int i = blockIdx.x * blockDim.x + threadIdx.x;
    if (i >= n) return;
    out[i] = f2h_bits(X[i]);
}

// ---------------- fp16 MFMA GEMM (round-9 verified structure) ---------------
// MODE 0 (head GEMM): writes Hb=fp16 + fused scores ssrc/sdst[yb][row].
// MODE 1 (enc lin): bias+relu -> fp16. MODE 2 (dec lin): bias+relu -> fp32.
template <int MODE>
__global__ __launch_bounds__(256) void k_gemm_f16(
    const u16* __restrict__ A, int lda,
    const u16* __restrict__ Bthi, const u16* __restrict__ Btlo,
    const float* __restrict__ bias,
    const float* __restrict__ asrc, const float* __restrict__ adst,
    float* __restrict__ C, u16* __restrict__ Cb1,
    float* __restrict__ ssrc, float* __restrict__ sdst,
    int ldc, int M, int K)
{
    __shared__ alignas(16) char smem[24576];
    __shared__ float sred[512];
    const int ASH = 0, BHI = 8192, BLO = 16384;
    int tid = threadIdx.x;
    int bm0 = blockIdx.x * 128;
    int yb = blockIdx.y;

    int wid = tid >> 6, lane = tid & 63;
    int wr = wid >> 1, wc = wid & 1;
    int fr = lane & 15, g = lane >> 4;

    f32x4 acc[4][4] = {};

    int arow = tid >> 1, ahalf = tid & 1;
    bool ain = (bm0 + arow) < M;
    const u16* aptr = A + (size_t)(bm0 + arow) * lda + ahalf * 16;
    int bcol = tid & 127, bhalf = tid >> 7;
    const u16* bph = Bthi + (size_t)yb * 128 * K + (size_t)bcol * K + bhalf * 16;
    const u16* bpl = Btlo + (size_t)yb * 128 * K + (size_t)bcol * K + bhalf * 16;

    int abase = arow * 64 + ahalf * 32;
    int asw = (arow & 7) << 4;
    int bbase = bcol * 64 + bhalf * 32;
    int bsw = (bcol & 7) << 4;

    uint4 va0, va1, vb0, vb1, vm0, vm1;
    if (ain) { va0 = *(const uint4*)(aptr); va1 = *(const uint4*)(aptr + 8); }
    else { va0 = make_uint4(0, 0, 0, 0); va1 = make_uint4(0, 0, 0, 0); }
    vb0 = *(const uint4*)(bph);
    vb1 = *(const uint4*)(bph + 8);
    vm0 = *(const uint4*)(bpl);
    vm1 = *(const uint4*)(bpl + 8);

    for (int k0 = 0; k0 < K; k0 += 32) {
        *(uint4*)(smem + ASH + ((abase +  0) ^ asw)) = va0;
        *(uint4*)(smem + ASH + ((abase + 16) ^ asw)) = va1;
        *(uint4*)(smem + BHI + ((bbase +  0) ^ bsw)) = vb0;
        *(uint4*)(smem + BHI + ((bbase + 16) ^ bsw)) = vb1;
        *(uint4*)(smem + BLO + ((bbase +  0) ^ bsw)) = vm0;
        *(uint4*)(smem + BLO + ((bbase + 16) ^ bsw)) = vm1;

        __syncthreads();

        if (k0 + 32 < K) {
            int kn = k0 + 32;
            if (ain) { va0 = *(const uint4*)(aptr + kn); va1 = *(const uint4*)(aptr + kn + 8); }
            else { va0 = make_uint4(0, 0, 0, 0); va1 = make_uint4(0, 0, 0, 0); }
            vb0 = *(const uint4*)(bph + kn);
            vb1 = *(const uint4*)(bph + kn + 8);
            vm0 = *(const uint4*)(bpl + kn);
            vm1 = *(const uint4*)(bpl + kn + 8);
        }

        f16x8 af[4], bh[4], bl[4];
#pragma unroll
        for (int mi = 0; mi < 4; ++mi) {
            int r = wr * 64 + mi * 16 + fr;
            int off = (r * 64 + g * 16) ^ ((r & 7) << 4);
            af[mi] = *(f16x8*)(smem + ASH + off);
        }
#pragma unroll
        for (int nj = 0; nj < 4; ++nj) {
            int c = wc * 64 + nj * 16 + fr;
            int off = (c * 64 + g * 16) ^ ((c & 7) << 4);
            bh[nj] = *(f16x8*)(smem + BHI + off);
            bl[nj] = *(f16x8*)(smem + BLO + off);
        }

#pragma unroll
        for (int mi = 0; mi < 4; ++mi)
#pragma unroll
            for (int nj = 0; nj < 4; ++nj) {
                acc[mi][nj] = __builtin_amdgcn_mfma_f32_16x16x32_f16(af[mi], bh[nj], acc[mi][nj], 0, 0, 0);
                acc[mi][nj] = __builtin_amdgcn_mfma_f32_16x16x32_f16(af[mi], bl[nj], acc[mi][nj], 0, 0, 0);
            }
        __syncthreads();
    }

    // ---- main output stores ----
#pragma unroll
    for (int mi = 0; mi < 4; ++mi) {
#pragma unroll
        for (int q = 0; q < 4; ++q) {
            int r = bm0 + wr * 64 + mi * 16 + g * 4 + q;
            if (r >= M) continue;
#pragma unroll
            for (int nj = 0; nj < 4; ++nj) {
                int c = wc * 64 + nj * 16 + fr;     // col within yb's 128
                float v = acc[mi][nj][q];
                if (MODE == 0) {
                    Cb1[(size_t)r * ldc + yb * 128 + c] = f2h_bits(v);
                } else if (MODE == 1) {
                    v += bias[c];
                    v = fmaxf(v, 0.f);
                    Cb1[(size_t)r * ldc + c] = f2h_bits(v);
                } else {
                    v += bias[c];
                    v = fmaxf(v, 0.f);
                    C[(size_t)r * ldc + c] = v;
                }
            }
        }
    }

    // ---- MODE 0: fused attention scores for head yb ----
    if (MODE == 0) {
        float asv[4], adv[4];
        const float* app = asrc + yb * FDIM;
        const float* dpp = adst + yb * FDIM;
#pragma unroll
        for (int nj = 0; nj < 4; ++nj) {
            int c = wc * 64 + nj * 16 + fr;
            asv[nj] = app[c];
            adv[nj] = dpp[c];
        }
#pragma unroll
        for (int mi = 0; mi < 4; ++mi) {
#pragma unroll
            for (int q = 0; q < 4; ++q) {
                float ps = 0.f, pd = 0.f;
#pragma unroll
                for (int nj = 0; nj < 4; ++nj) {
                    ps += acc[mi][nj][q] * asv[nj];
                    pd += acc[mi][nj][q] * adv[nj];
                }
#pragma unroll
                for (int o = 1; o < 16; o <<= 1) {
                    ps += __shfl_xor(ps, o);
                    pd += __shfl_xor(pd, o);
                }
                if (fr == 0) {
                    int row128 = wr * 64 + mi * 16 + g * 4 + q;
                    sred[(row128 * 2 + wc) * 2 + 0] = ps;
                    sred[(row128 * 2 + wc) * 2 + 1] = pd;
                }
            }
        }
        __syncthreads();
        {
            int rg = tid >> 1;          // 0..127
            int which = tid & 1;
            int r = bm0 + rg;
            if (r < M) {
                float v = sred[(rg * 2 + 0) * 2 + which] + sred[(rg * 2 + 1) * 2 + which];
                float* dstp = which ? sdst : ssrc;
                dstp[(size_t)yb * M + r] = v;
            }
        }
    }
}

// ---------------- alpha pre-pass --------------------------------------------
// 1 wave/node, lanes over edges. Computes per-edge softmax weight for all 4
// heads (no max pass: scores O(1), exp safe in fp32), writes edata[h][i] =
// (weight bits, src), accumulates per-head denominators.
__global__ __launch_bounds__(64) void k_alpha(
    const int* __restrict__ off, const int* __restrict__ csr,
    const float* __restrict__ ssrc, const float* __restrict__ sdst,
    uint2* __restrict__ edata, float* __restrict__ denom, int N, int Etot) {
    int n = blockIdx.x;
    int lane = threadIdx.x;
    int o0 = off[n], o1 = off[n + 1];
    float sd[4];
#pragma unroll
    for (int h = 0; h < HEADS; ++h) sd[h] = sdst[(size_t)h * N + n];
    float dsum[4] = {0.f, 0.f, 0.f, 0.f};
    for (int i = o0 + lane; i < o1; i += 64) {
        int s = csr[i];
#pragma unroll
        for (int h = 0; h < HEADS; ++h) {
            float e = ssrc[(size_t)h * N + s] + sd[h];
            e = e >= 0.f ? e : 0.2f * e;
            float wgt = __expf(e);
            dsum[h] += wgt;
            edata[(size_t)h * Etot + i] = make_uint2(__float_as_uint(wgt), (unsigned)s);
        }
    }
#pragma unroll
    for (int h = 0; h < HEADS; ++h)
        for (int o = 32; o; o >>= 1) dsum[h] += __shfl_xor(dsum[h], o);
    if (lane == 0) {
#pragma unroll
        for (int h = 0; h < HEADS; ++h) denom[(size_t)h * N + n] = dsum[h];
    }
}

// ---------------- XCD-pinned column-slab gather aggregate -------------------
// bid%8 = slab (empirically = XCD on MI355X round-robin dispatch). Block =
// 4 waves = 4 nodes, one 64-col slab. Lane owns 1 column; per edge: uniform
// 8B edata load + 128B/wave gather from Hb slab (L2-resident per XCD).
__global__ __launch_bounds__(256) void k_agg_slab(
    const u16* __restrict__ Hb, const int* __restrict__ off,
    const uint2* __restrict__ edata, const float* __restrict__ denom,
    const float* __restrict__ bvec, u16* __restrict__ Gh, int N, int Etot) {
    int bid = blockIdx.x;
    int slab = bid & 7;
    int n = (bid >> 3) * 4 + (threadIdx.x >> 6);
    if (n >= N) return;
    int lane = threadIdx.x & 63;
    int h = slab >> 1;
    int col = slab * 64 + lane;
    const uint2* ed = edata + (size_t)h * Etot;
    int o0 = __builtin_amdgcn_readfirstlane(off[n]);
    int o1 = __builtin_amdgcn_readfirstlane(off[n + 1]);
    float acc = 0.f;
    int i = o0;
    for (; i + 4 <= o1; i += 4) {
        uint2 e0 = ed[i + 0], e1 = ed[i + 1], e2 = ed[i + 2], e3 = ed[i + 3];
        u16 g0 = Hb[(size_t)e0.y * HCAT + col];
        u16 g1 = Hb[(size_t)e1.y * HCAT + col];
        u16 g2 = Hb[(size_t)e2.y * HCAT + col];
        u16 g3 = Hb[(size_t)e3.y * HCAT + col];
        acc += __uint_as_float(e0.x) * h2f_bits(g0);
        acc += __uint_as_float(e1.x) * h2f_bits(g1);
        acc += __uint_as_float(e2.x) * h2f_bits(g2);
        acc += __uint_as_float(e3.x) * h2f_bits(g3);
    }
    for (; i < o1; ++i) {
        uint2 e = ed[i];
        acc += __uint_as_float(e.x) * h2f_bits(Hb[(size_t)e.y * HCAT + col]);
    }
    float inv = 1.f / denom[(size_t)h * N + n];
    float v = acc * inv + bvec[h * FDIM + (slab & 1) * 64 + lane];
    Gh[(size_t)n * HCAT + col] = f2h_bits(v);
}

// ---------------------------------------------------------------------------
extern "C" void kernel_launch(void* const* d_in, const int* in_sizes, int n_in,
                              void* d_out, int out_size, void* d_ws, size_t ws_size,
                              hipStream_t stream) {
    const float* x = (const float*)d_in[0];
    const void* ei = d_in[1];
    const float* encW = (const float*)d_in[2];
    const float* enc_asrc = (const float*)d_in[3];
    const float* enc_adst = (const float*)d_in[4];
    const float* enc_b = (const float*)d_in[5];
    const float* enc_linW = (const float*)d_in[6];
    const float* enc_linb = (const float*)d_in[7];
    const float* decW = (const float*)d_in[8];
    const float* dec_asrc = (const float*)d_in[9];
    const float* dec_adst = (const float*)d_in[10];
    const float* dec_b = (const float*)d_in[11];
    const float* dec_linW = (const float*)d_in[12];
    const float* dec_linb = (const float*)d_in[13];

    int N = in_sizes[0] / FDIM;
    int E = in_sizes[1] / 2;
    int Etot = E + N;

    char* w = (char*)d_ws;
    size_t o = 0;
    auto alloc = [&](size_t bytes) -> char* {
        char* p = w + o;
        o += (bytes + 255) & ~(size_t)255;
        return p;
    };
    int* flag = (int*)alloc(4);
    int* deg = (int*)alloc((size_t)N * 4);
    int* off = (int*)alloc((size_t)(N + 1) * 4);
    int* cur = (int*)alloc((size_t)N * 4);
    int* csr = (int*)alloc((size_t)Etot * 4);
    int* bsum = (int*)alloc(SCAN_BLOCKS * 4);
    int* bbase = (int*)alloc(SCAN_BLOCKS * 4);
    float* ssrc = (float*)alloc((size_t)HEADS * N * 4);
    float* sdst = (float*)alloc((size_t)HEADS * N * 4);
    float* denom = (float*)alloc((size_t)HEADS * N * 4);
    uint2* edata = (uint2*)alloc((size_t)HEADS * Etot * 8);
    u16* Gh = (u16*)alloc((size_t)N * HCAT * 2);
    u16* Hb = (u16*)alloc((size_t)N * HCAT * 2);
    u16* xh = (u16*)alloc((size_t)N * FDIM * 2);
    u16* X2h = (u16*)alloc((size_t)N * FDIM * 2);
    u16* encWt_h = (u16*)alloc((size_t)HEADS * FDIM * FDIM * 2);
    u16* encWt_l = (u16*)alloc((size_t)HEADS * FDIM * FDIM * 2);
    u16* linWt_h = (u16*)alloc((size_t)HCAT * FDIM * 2);
    u16* linWt_l = (u16*)alloc((size_t)HCAT * FDIM * 2);
    u16* decWt_h = (u16*)alloc((size_t)HEADS * FDIM * FDIM * 2);
    u16* decWt_l = (u16*)alloc((size_t)HEADS * FDIM * FDIM * 2);
    u16* dlinWt_h = (u16*)alloc((size_t)HCAT * FDIM * 2);
    u16* dlinWt_l = (u16*)alloc((size_t)HCAT * FDIM * 2);
    (void)ws_size;

    // CSR build
    k_detect<<<1, 64, 0, stream>>>(ei, E, N, flag);
    k_zero_i32<<<(N + 255) / 256, 256, 0, stream>>>(deg, N);
    k_count<<<(Etot + 255) / 256, 256, 0, stream>>>(ei, flag, E, N, deg);
    k_scan1<<<SCAN_BLOCKS, SCAN_TPB, 0, stream>>>(deg, bsum, N);
    k_scan2<<<1, SCAN_BLOCKS, 0, stream>>>(bsum, bbase, off + N);
    k_scan3<<<SCAN_BLOCKS, SCAN_TPB, 0, stream>>>(deg, bbase, off, cur, N);
    k_fill<<<(Etot + 255) / 256, 256, 0, stream>>>(ei, flag, E, N, cur, csr);

    // operand prep
    int wtot = HEADS * FDIM * FDIM;
    k_splitw<<<(wtot + 255) / 256, 256, 0, stream>>>(encW, encWt_h, encWt_l, HEADS, FDIM);
    k_splitw<<<(wtot + 255) / 256, 256, 0, stream>>>(enc_linW, linWt_h, linWt_l, 1, HCAT);
    k_splitw<<<(wtot + 255) / 256, 256, 0, stream>>>(decW, decWt_h, decWt_l, HEADS, FDIM);
    k_splitw<<<(wtot + 255) / 256, 256, 0, stream>>>(dec_linW, dlinWt_h, dlinWt_l, 1, HCAT);
    k_cvt_f16<<<(N * FDIM + 255) / 256, 256, 0, stream>>>(x, xh, N * FDIM);

    int mblocks = (N + 127) / 128;
    int aggblocks = ((N + 3) / 4) * 8;

    // ---- encoder ----
    k_gemm_f16<0><<<dim3(mblocks, 4), 256, 0, stream>>>(
        xh, FDIM, encWt_h, encWt_l, nullptr, enc_asrc, enc_adst,
        nullptr, Hb, ssrc, sdst, HCAT, N, FDIM);
    k_alpha<<<N, 64, 0, stream>>>(off, csr, ssrc, sdst, edata, denom, N, Etot);
    k_agg_slab<<<aggblocks, 256, 0, stream>>>(Hb, off, edata, denom, enc_b, Gh, N, Etot);
    k_gemm_f16<1><<<dim3(mblocks, 1), 256, 0, stream>>>(
        Gh, HCAT, linWt_h, linWt_l, enc_linb, nullptr, nullptr,
        nullptr, X2h, nullptr, nullptr, FDIM, N, HCAT);

    // ---- decoder ----
    k_gemm_f16<0><<<dim3(mblocks, 4), 256, 0, stream>>>(
        X2h, FDIM, decWt_h, decWt_l, nullptr, dec_asrc, dec_adst,
        nullptr, Hb, ssrc, sdst, HCAT, N, FDIM);
    k_alpha<<<N, 64, 0, stream>>>(off, csr, ssrc, sdst, edata, denom, N, Etot);
    k_agg_slab<<<aggblocks, 256, 0, stream>>>(Hb, off, edata, denom, dec_b, Gh, N, Etot);
    k_gemm_f16<2><<<dim3(mblocks, 1), 256, 0, stream>>>(
        Gh, HCAT, dlinWt_h, dlinWt_l, dec_linb, nullptr, nullptr,
        (float*)d_out, nullptr, nullptr, nullptr, FDIM, N, HCAT);
}

// Round 13
// 513.906 us; speedup vs baseline: 1.3274x; 1.3274x over previous
//
#include <hip/hip_runtime.h>
#include <hip/hip_fp16.h>
#include <cstdint>
#include <cstddef>

// ---------------------------------------------------------------------------
// GraphAutoencoder: 2 x [4-head GATConv(128->128) -> concat -> Linear(512->128) -> ReLU]
// N=50000, E=800000 (+N self-loops). fp32 in/out.
// GEMMs: fp16 MFMA (round-9 verified, byte-exact: runtime K, async-STAGE
//   split, scattered stores). A = fp16 activations; B = fp16 hi/lo weights.
// Scores fused in head GEMM. Aggregate: round-9 fp16 row gather (HBM floor).
// This round: launch consolidation only (detect+zero merged; 4 splitw + cvt
//   merged into one k_prep). 18 -> 13 launches.
// ---------------------------------------------------------------------------

#define FDIM   128
#define HEADS  4
#define HCAT   512

typedef unsigned short u16;
typedef __attribute__((ext_vector_type(4))) float f32x4;
typedef __attribute__((ext_vector_type(8))) _Float16 f16x8;

__device__ __forceinline__ u16 f2h_bits(float f) {
    _Float16 h = (_Float16)f;
    return *(u16*)&h;
}

// ---------------- edge dtype detection + deg zero (merged) ------------------
__global__ void k_detect_zero(const void* ei, int E, int N, int* flag, int* deg) {
    int i = blockIdx.x * blockDim.x + threadIdx.x;
    if (i < N) deg[i] = 0;
    if (i == 0) {
        const long long* p = (const long long*)ei;
        int bad = 0;
        int n = E < 64 ? E : 64;
        for (int k = 0; k < n; ++k) {
            long long v = p[k];
            if (v < 0 || v >= (long long)N) bad = 1;
        }
        *flag = bad;  // 1 => int32, 0 => int64
    }
}

__device__ __forceinline__ int edge_at(const void* ei, int is32, long long pos) {
    return is32 ? ((const int*)ei)[pos] : (int)(((const long long*)ei)[pos]);
}

__global__ void k_count(const void* ei, const int* flag, int E, int N, int* deg) {
    int e = blockIdx.x * blockDim.x + threadIdx.x;
    int Etot = E + N;
    if (e >= Etot) return;
    int is32 = *flag;
    int dst = (e < E) ? edge_at(ei, is32, (long long)E + e) : (e - E);
    atomicAdd(&deg[dst], 1);
}

// ---------------- multi-block exclusive scan --------------------------------
#define SCAN_BLOCKS 256
#define SCAN_TPB    256

__global__ __launch_bounds__(SCAN_TPB) void k_scan1(const int* __restrict__ deg,
                                                    int* __restrict__ bsum, int N) {
    __shared__ int sdata[SCAN_TPB];
    int b = blockIdx.x;
    int chunk = (N + SCAN_BLOCKS - 1) / SCAN_BLOCKS;
    int start = b * chunk;
    int end = start + chunk;
    if (start > N) start = N;
    if (end > N) end = N;
    int s = 0;
    for (int i = start + threadIdx.x; i < end; i += SCAN_TPB) s += deg[i];
    sdata[threadIdx.x] = s;
    __syncthreads();
    for (int o = SCAN_TPB / 2; o; o >>= 1) {
        if (threadIdx.x < o) sdata[threadIdx.x] += sdata[threadIdx.x + o];
        __syncthreads();
    }
    if (threadIdx.x == 0) bsum[b] = sdata[0];
}

__global__ __launch_bounds__(SCAN_BLOCKS) void k_scan2(const int* __restrict__ bsum,
                                                       int* __restrict__ bbase,
                                                       int* __restrict__ off_last) {
    __shared__ int sdata[SCAN_BLOCKS];
    int t = threadIdx.x;
    sdata[t] = bsum[t];
    __syncthreads();
    for (int o = 1; o < SCAN_BLOCKS; o <<= 1) {
        int v = (t >= o) ? sdata[t - o] : 0;
        __syncthreads();
        sdata[t] += v;
        __syncthreads();
    }
    bbase[t] = (t == 0) ? 0 : sdata[t - 1];
    if (t == SCAN_BLOCKS - 1) *off_last = sdata[t];
}

__global__ __launch_bounds__(SCAN_TPB) void k_scan3(const int* __restrict__ deg,
                                                    const int* __restrict__ bbase,
                                                    int* __restrict__ off,
                                                    int* __restrict__ cur, int N) {
    __shared__ int sdata[SCAN_TPB];
    int b = blockIdx.x;
    int chunk = (N + SCAN_BLOCKS - 1) / SCAN_BLOCKS;
    int start = b * chunk;
    int end = start + chunk;
    if (start > N) start = N;
    if (end > N) end = N;
    int base = bbase[b];
    for (int i0 = start; i0 < end; i0 += SCAN_TPB) {
        int i = i0 + threadIdx.x;
        int v = (i < end) ? deg[i] : 0;
        sdata[threadIdx.x] = v;
        __syncthreads();
        for (int o = 1; o < SCAN_TPB; o <<= 1) {
            int u = (threadIdx.x >= o) ? sdata[threadIdx.x - o] : 0;
            __syncthreads();
            sdata[threadIdx.x] += u;
            __syncthreads();
        }
        if (i < end) {
            int excl = base + sdata[threadIdx.x] - v;
            off[i] = excl;
            cur[i] = excl;
        }
        base += sdata[SCAN_TPB - 1];
        __syncthreads();
    }
}

__global__ void k_fill(const void* ei, const int* flag, int E, int N, int* cur, int* csr) {
    int e = blockIdx.x * blockDim.x + threadIdx.x;
    int Etot = E + N;
    if (e >= Etot) return;
    int is32 = *flag;
    int src, dst;
    if (e < E) {
        src = edge_at(ei, is32, e);
        dst = edge_at(ei, is32, (long long)E + e);
    } else {
        src = e - E;
        dst = e - E;
    }
    int pos = atomicAdd(&cur[dst], 1);
    csr[pos] = src;
}

// ---------------- merged operand prep ---------------------------------------
// idx < Nf: xh = fp16(x). Then four weight splits, each HEADS*FDIM*FDIM elems:
// W [nblk][K][128] fp32 -> hi/lo fp16 [nblk*128 cols][K] (same math as the
// original k_splitw, range-dispatched).
__global__ void k_prep(const float* __restrict__ x, u16* __restrict__ xh, int Nf,
                       const float* __restrict__ encW, u16* __restrict__ eh, u16* __restrict__ el,
                       const float* __restrict__ linW, u16* __restrict__ lh, u16* __restrict__ ll,
                       const float* __restrict__ decW, u16* __restrict__ dh, u16* __restrict__ dl,
                       const float* __restrict__ dlW, u16* __restrict__ dh2, u16* __restrict__ dl2) {
    int i = blockIdx.x * blockDim.x + threadIdx.x;
    if (i < Nf) {
        xh[i] = f2h_bits(x[i]);
        return;
    }
    int j = i - Nf;
    const int WSZ = HEADS * FDIM * FDIM;
    const float* W;
    u16 *hi, *lo;
    int K;
    if (j < WSZ)            { W = encW; hi = eh;  lo = el;  K = FDIM; }
    else if (j < 2 * WSZ)   { W = linW; hi = lh;  lo = ll;  K = HCAT; j -= WSZ; }
    else if (j < 3 * WSZ)   { W = decW; hi = dh;  lo = dl;  K = FDIM; j -= 2 * WSZ; }
    else if (j < 4 * WSZ)   { W = dlW;  hi = dh2; lo = dl2; K = HCAT; j -= 3 * WSZ; }
    else return;
    int blk = j / (K * 128);
    int rem = j - blk * K * 128;
    int k = rem >> 7, col = rem & 127;
    float v = W[j];
    _Float16 hh = (_Float16)v;
    _Float16 llv = (_Float16)(v - (float)hh);
    size_t o = (size_t)blk * 128 * K + (size_t)col * K + k;
    hi[o] = *(u16*)&hh;
    lo[o] = *(u16*)&llv;
}

// ---------------- fp16 MFMA GEMM (round-9 verified, byte-exact) -------------
// MODE 0 (head GEMM): writes Hb=fp16 + fused scores ssrc/sdst[yb][row].
// MODE 1 (enc lin): bias+relu -> fp16. MODE 2 (dec lin): bias+relu -> fp32.
template <int MODE>
__global__ __launch_bounds__(256) void k_gemm_f16(
    const u16* __restrict__ A, int lda,
    const u16* __restrict__ Bthi, const u16* __restrict__ Btlo,
    const float* __restrict__ bias,
    const float* __restrict__ asrc, const float* __restrict__ adst,
    float* __restrict__ C, u16* __restrict__ Cb1,
    float* __restrict__ ssrc, float* __restrict__ sdst,
    int ldc, int M, int K)
{
    __shared__ alignas(16) char smem[24576];
    __shared__ float sred[512];
    const int ASH = 0, BHI = 8192, BLO = 16384;
    int tid = threadIdx.x;
    int bm0 = blockIdx.x * 128;
    int yb = blockIdx.y;

    int wid = tid >> 6, lane = tid & 63;
    int wr = wid >> 1, wc = wid & 1;
    int fr = lane & 15, g = lane >> 4;

    f32x4 acc[4][4] = {};

    int arow = tid >> 1, ahalf = tid & 1;
    bool ain = (bm0 + arow) < M;
    const u16* aptr = A + (size_t)(bm0 + arow) * lda + ahalf * 16;
    int bcol = tid & 127, bhalf = tid >> 7;
    const u16* bph = Bthi + (size_t)yb * 128 * K + (size_t)bcol * K + bhalf * 16;
    const u16* bpl = Btlo + (size_t)yb * 128 * K + (size_t)bcol * K + bhalf * 16;

    int abase = arow * 64 + ahalf * 32;
    int asw = (arow & 7) << 4;
    int bbase = bcol * 64 + bhalf * 32;
    int bsw = (bcol & 7) << 4;

    // prologue: issue loads for tile 0
    uint4 va0, va1, vb0, vb1, vm0, vm1;
    if (ain) { va0 = *(const uint4*)(aptr); va1 = *(const uint4*)(aptr + 8); }
    else { va0 = make_uint4(0, 0, 0, 0); va1 = make_uint4(0, 0, 0, 0); }
    vb0 = *(const uint4*)(bph);
    vb1 = *(const uint4*)(bph + 8);
    vm0 = *(const uint4*)(bpl);
    vm1 = *(const uint4*)(bpl + 8);

    for (int k0 = 0; k0 < K; k0 += 32) {
        // stage the already-loaded tile (vmcnt wait lands here, covered by
        // the previous iteration's MFMA block)
        *(uint4*)(smem + ASH + ((abase +  0) ^ asw)) = va0;
        *(uint4*)(smem + ASH + ((abase + 16) ^ asw)) = va1;
        *(uint4*)(smem + BHI + ((bbase +  0) ^ bsw)) = vb0;
        *(uint4*)(smem + BHI + ((bbase + 16) ^ bsw)) = vb1;
        *(uint4*)(smem + BLO + ((bbase +  0) ^ bsw)) = vm0;
        *(uint4*)(smem + BLO + ((bbase + 16) ^ bsw)) = vm1;

        __syncthreads();

        // issue next tile's loads now; consumed at next iteration's stage
        if (k0 + 32 < K) {
            int kn = k0 + 32;
            if (ain) { va0 = *(const uint4*)(aptr + kn); va1 = *(const uint4*)(aptr + kn + 8); }
            else { va0 = make_uint4(0, 0, 0, 0); va1 = make_uint4(0, 0, 0, 0); }
            vb0 = *(const uint4*)(bph + kn);
            vb1 = *(const uint4*)(bph + kn + 8);
            vm0 = *(const uint4*)(bpl + kn);
            vm1 = *(const uint4*)(bpl + kn + 8);
        }

        f16x8 af[4], bh[4], bl[4];
#pragma unroll
        for (int mi = 0; mi < 4; ++mi) {
            int r = wr * 64 + mi * 16 + fr;
            int off = (r * 64 + g * 16) ^ ((r & 7) << 4);
            af[mi] = *(f16x8*)(smem + ASH + off);
        }
#pragma unroll
        for (int nj = 0; nj < 4; ++nj) {
            int c = wc * 64 + nj * 16 + fr;
            int off = (c * 64 + g * 16) ^ ((c & 7) << 4);
            bh[nj] = *(f16x8*)(smem + BHI + off);
            bl[nj] = *(f16x8*)(smem + BLO + off);
        }

#pragma unroll
        for (int mi = 0; mi < 4; ++mi)
#pragma unroll
            for (int nj = 0; nj < 4; ++nj) {
                acc[mi][nj] = __builtin_amdgcn_mfma_f32_16x16x32_f16(af[mi], bh[nj], acc[mi][nj], 0, 0, 0);
                acc[mi][nj] = __builtin_amdgcn_mfma_f32_16x16x32_f16(af[mi], bl[nj], acc[mi][nj], 0, 0, 0);
            }
        __syncthreads();
    }

    // ---- main output stores ----
#pragma unroll
    for (int mi = 0; mi < 4; ++mi) {
#pragma unroll
        for (int q = 0; q < 4; ++q) {
            int r = bm0 + wr * 64 + mi * 16 + g * 4 + q;
            if (r >= M) continue;
#pragma unroll
            for (int nj = 0; nj < 4; ++nj) {
                int c = wc * 64 + nj * 16 + fr;     // col within yb's 128
                float v = acc[mi][nj][q];
                if (MODE == 0) {
                    Cb1[(size_t)r * ldc + yb * 128 + c] = f2h_bits(v);
                } else if (MODE == 1) {
                    v += bias[c];
                    v = fmaxf(v, 0.f);
                    Cb1[(size_t)r * ldc + c] = f2h_bits(v);
                } else {
                    v += bias[c];
                    v = fmaxf(v, 0.f);
                    C[(size_t)r * ldc + c] = v;
                }
            }
        }
    }

    // ---- MODE 0: fused attention scores for head yb ----
    if (MODE == 0) {
        float asv[4], adv[4];
        const float* app = asrc + yb * FDIM;
        const float* dpp = adst + yb * FDIM;
#pragma unroll
        for (int nj = 0; nj < 4; ++nj) {
            int c = wc * 64 + nj * 16 + fr;
            asv[nj] = app[c];
            adv[nj] = dpp[c];
        }
#pragma unroll
        for (int mi = 0; mi < 4; ++mi) {
#pragma unroll
            for (int q = 0; q < 4; ++q) {
                float ps = 0.f, pd = 0.f;
#pragma unroll
                for (int nj = 0; nj < 4; ++nj) {
                    ps += acc[mi][nj][q] * asv[nj];
                    pd += acc[mi][nj][q] * adv[nj];
                }
#pragma unroll
                for (int o = 1; o < 16; o <<= 1) {
                    ps += __shfl_xor(ps, o);
                    pd += __shfl_xor(pd, o);
                }
                if (fr == 0) {
                    int row128 = wr * 64 + mi * 16 + g * 4 + q;
                    sred[(row128 * 2 + wc) * 2 + 0] = ps;
                    sred[(row128 * 2 + wc) * 2 + 1] = pd;
                }
            }
        }
        __syncthreads();
        {
            int rg = tid >> 1;          // 0..127
            int which = tid & 1;
            int r = bm0 + rg;
            if (r < M) {
                float v = sred[(rg * 2 + 0) * 2 + which] + sred[(rg * 2 + 1) * 2 + which];
                float* dstp = which ? sdst : ssrc;
                dstp[(size_t)yb * M + r] = v;
            }
        }
    }
}

// ---------------- segment softmax + fp16 gather aggregate (round-9) ---------
__global__ __launch_bounds__(64) void k_aggregate(
    const u16* __restrict__ Hb, const int* __restrict__ off,
    const int* __restrict__ csr, const float* __restrict__ ssrc,
    const float* __restrict__ sdst, const float* __restrict__ bvec,
    u16* __restrict__ Gh, int N) {
    int n = blockIdx.x;
    int lane = threadIdx.x;
    int o0 = __builtin_amdgcn_readfirstlane(off[n]);
    int o1 = __builtin_amdgcn_readfirstlane(off[n + 1]);
    int h = lane >> 4;
    int col0 = lane * 8;
    float sdh = sdst[(size_t)h * N + n];
    const float* ssrc_h = ssrc + (size_t)h * N;
    float denom = 0.f;
    float acc[8] = {0.f, 0.f, 0.f, 0.f, 0.f, 0.f, 0.f, 0.f};

    auto body = [&](float ew, uint4 hv) {
        const __half2* hp = (const __half2*)&hv;
#pragma unroll
        for (int j = 0; j < 4; ++j) {
            float2 f = __half22float2(hp[j]);
            acc[2 * j]     += ew * f.x;
            acc[2 * j + 1] += ew * f.y;
        }
    };

    int i = o0;
    for (; i + 4 <= o1; i += 4) {
        int s0 = csr[i + 0], s1 = csr[i + 1], s2 = csr[i + 2], s3 = csr[i + 3];
        uint4 v0 = *(const uint4*)&Hb[(size_t)s0 * HCAT + col0];
        uint4 v1 = *(const uint4*)&Hb[(size_t)s1 * HCAT + col0];
        uint4 v2 = *(const uint4*)&Hb[(size_t)s2 * HCAT + col0];
        uint4 v3 = *(const uint4*)&Hb[(size_t)s3 * HCAT + col0];
        float e0 = ssrc_h[s0] + sdh, e1 = ssrc_h[s1] + sdh;
        float e2 = ssrc_h[s2] + sdh, e3 = ssrc_h[s3] + sdh;
        e0 = e0 >= 0.f ? e0 : 0.2f * e0;
        e1 = e1 >= 0.f ? e1 : 0.2f * e1;
        e2 = e2 >= 0.f ? e2 : 0.2f * e2;
        e3 = e3 >= 0.f ? e3 : 0.2f * e3;
        float w0 = __expf(e0), w1 = __expf(e1), w2 = __expf(e2), w3 = __expf(e3);
        denom += (w0 + w1) + (w2 + w3);
        body(w0, v0);
        body(w1, v1);
        body(w2, v2);
        body(w3, v3);
    }
    for (; i < o1; ++i) {
        int s = csr[i];
        uint4 v = *(const uint4*)&Hb[(size_t)s * HCAT + col0];
        float e = ssrc_h[s] + sdh;
        e = e >= 0.f ? e : 0.2f * e;
        float ew = __expf(e);
        denom += ew;
        body(ew, v);
    }

    float inv = 1.f / denom;
    u16 hs[8];
#pragma unroll
    for (int k = 0; k < 8; ++k) {
        int col = col0 + k;
        float v = acc[k] * inv + bvec[h * FDIM + (col & 127)];
        hs[k] = f2h_bits(v);
    }
    *(uint4*)&Gh[(size_t)n * HCAT + col0] = *(uint4*)hs;
}

// ---------------------------------------------------------------------------
extern "C" void kernel_launch(void* const* d_in, const int* in_sizes, int n_in,
                              void* d_out, int out_size, void* d_ws, size_t ws_size,
                              hipStream_t stream) {
    const float* x = (const float*)d_in[0];
    const void* ei = d_in[1];
    const float* encW = (const float*)d_in[2];
    const float* enc_asrc = (const float*)d_in[3];
    const float* enc_adst = (const float*)d_in[4];
    const float* enc_b = (const float*)d_in[5];
    const float* enc_linW = (const float*)d_in[6];
    const float* enc_linb = (const float*)d_in[7];
    const float* decW = (const float*)d_in[8];
    const float* dec_asrc = (const float*)d_in[9];
    const float* dec_adst = (const float*)d_in[10];
    const float* dec_b = (const float*)d_in[11];
    const float* dec_linW = (const float*)d_in[12];
    const float* dec_linb = (const float*)d_in[13];

    int N = in_sizes[0] / FDIM;
    int E = in_sizes[1] / 2;
    int Etot = E + N;

    char* w = (char*)d_ws;
    size_t o = 0;
    auto alloc = [&](size_t bytes) -> char* {
        char* p = w + o;
        o += (bytes + 255) & ~(size_t)255;
        return p;
    };
    int* flag = (int*)alloc(4);
    int* deg = (int*)alloc((size_t)N * 4);
    int* off = (int*)alloc((size_t)(N + 1) * 4);
    int* cur = (int*)alloc((size_t)N * 4);
    int* csr = (int*)alloc((size_t)Etot * 4);
    int* bsum = (int*)alloc(SCAN_BLOCKS * 4);
    int* bbase = (int*)alloc(SCAN_BLOCKS * 4);
    float* ssrc = (float*)alloc((size_t)HEADS * N * 4);
    float* sdst = (float*)alloc((size_t)HEADS * N * 4);
    u16* Gh = (u16*)alloc((size_t)N * HCAT * 2);
    u16* Hb = (u16*)alloc((size_t)N * HCAT * 2);
    u16* xh = (u16*)alloc((size_t)N * FDIM * 2);
    u16* X2h = (u16*)alloc((size_t)N * FDIM * 2);
    u16* encWt_h = (u16*)alloc((size_t)HEADS * FDIM * FDIM * 2);
    u16* encWt_l = (u16*)alloc((size_t)HEADS * FDIM * FDIM * 2);
    u16* linWt_h = (u16*)alloc((size_t)HCAT * FDIM * 2);
    u16* linWt_l = (u16*)alloc((size_t)HCAT * FDIM * 2);
    u16* decWt_h = (u16*)alloc((size_t)HEADS * FDIM * FDIM * 2);
    u16* decWt_l = (u16*)alloc((size_t)HEADS * FDIM * FDIM * 2);
    u16* dlinWt_h = (u16*)alloc((size_t)HCAT * FDIM * 2);
    u16* dlinWt_l = (u16*)alloc((size_t)HCAT * FDIM * 2);
    (void)ws_size;

    // CSR build
    k_detect_zero<<<(N + 255) / 256, 256, 0, stream>>>(ei, E, N, flag, deg);
    k_count<<<(Etot + 255) / 256, 256, 0, stream>>>(ei, flag, E, N, deg);
    k_scan1<<<SCAN_BLOCKS, SCAN_TPB, 0, stream>>>(deg, bsum, N);
    k_scan2<<<1, SCAN_BLOCKS, 0, stream>>>(bsum, bbase, off + N);
    k_scan3<<<SCAN_BLOCKS, SCAN_TPB, 0, stream>>>(deg, bbase, off, cur, N);
    k_fill<<<(Etot + 255) / 256, 256, 0, stream>>>(ei, flag, E, N, cur, csr);

    // merged operand prep (xh + 4 weight splits)
    int Nf = N * FDIM;
    int prep_total = Nf + 4 * HEADS * FDIM * FDIM;
    k_prep<<<(prep_total + 255) / 256, 256, 0, stream>>>(
        x, xh, Nf,
        encW, encWt_h, encWt_l,
        enc_linW, linWt_h, linWt_l,
        decW, decWt_h, decWt_l,
        dec_linW, dlinWt_h, dlinWt_l);

    int mblocks = (N + 127) / 128;

    // ---- encoder ----
    k_gemm_f16<0><<<dim3(mblocks, 4), 256, 0, stream>>>(
        xh, FDIM, encWt_h, encWt_l, nullptr, enc_asrc, enc_adst,
        nullptr, Hb, ssrc, sdst, HCAT, N, FDIM);
    k_aggregate<<<N, 64, 0, stream>>>(Hb, off, csr, ssrc, sdst, enc_b, Gh, N);
    k_gemm_f16<1><<<dim3(mblocks, 1), 256, 0, stream>>>(
        Gh, HCAT, linWt_h, linWt_l, enc_linb, nullptr, nullptr,
        nullptr, X2h, nullptr, nullptr, FDIM, N, HCAT);

    // ---- decoder ----
    k_gemm_f16<0><<<dim3(mblocks, 4), 256, 0, stream>>>(
        X2h, FDIM, decWt_h, decWt_l, nullptr, dec_asrc, dec_adst,
        nullptr, Hb, ssrc, sdst, HCAT, N, FDIM);
    k_aggregate<<<N, 64, 0, stream>>>(Hb, off, csr, ssrc, sdst, dec_b, Gh, N);
    k_gemm_f16<2><<<dim3(mblocks, 1), 256, 0, stream>>>(
        Gh, HCAT, dlinWt_h, dlinWt_l, dec_linb, nullptr, nullptr,
        (float*)d_out, nullptr, nullptr, nullptr, FDIM, N, HCAT);
}

// Round 14
// 491.120 us; speedup vs baseline: 1.3890x; 1.0464x over previous
//
#include <hip/hip_runtime.h>
#include <hip/hip_fp16.h>
#include <cstdint>
#include <cstddef>

// ---------------------------------------------------------------------------
// GraphAutoencoder: 2 x [4-head GATConv(128->128) -> concat -> Linear(512->128) -> ReLU]
// N=50000, E=800000 (+N self-loops). fp32 in/out.
// GEMMs: fp16 MFMA (round-9 verified loop; weights now SINGLE fp16 — lo term
//   dropped, error +~3e-4 well within budget). Scores fused in head GEMM.
// Aggregate: round-9 fp16 row gather (at its random-gather memory floor).
// ---------------------------------------------------------------------------

#define FDIM   128
#define HEADS  4
#define HCAT   512

typedef unsigned short u16;
typedef __attribute__((ext_vector_type(4))) float f32x4;
typedef __attribute__((ext_vector_type(8))) _Float16 f16x8;

__device__ __forceinline__ u16 f2h_bits(float f) {
    _Float16 h = (_Float16)f;
    return *(u16*)&h;
}

// ---------------- edge dtype detection + deg zero (merged) ------------------
__global__ void k_detect_zero(const void* ei, int E, int N, int* flag, int* deg) {
    int i = blockIdx.x * blockDim.x + threadIdx.x;
    if (i < N) deg[i] = 0;
    if (i == 0) {
        const long long* p = (const long long*)ei;
        int bad = 0;
        int n = E < 64 ? E : 64;
        for (int k = 0; k < n; ++k) {
            long long v = p[k];
            if (v < 0 || v >= (long long)N) bad = 1;
        }
        *flag = bad;  // 1 => int32, 0 => int64
    }
}

__device__ __forceinline__ int edge_at(const void* ei, int is32, long long pos) {
    return is32 ? ((const int*)ei)[pos] : (int)(((const long long*)ei)[pos]);
}

__global__ void k_count(const void* ei, const int* flag, int E, int N, int* deg) {
    int e = blockIdx.x * blockDim.x + threadIdx.x;
    int Etot = E + N;
    if (e >= Etot) return;
    int is32 = *flag;
    int dst = (e < E) ? edge_at(ei, is32, (long long)E + e) : (e - E);
    atomicAdd(&deg[dst], 1);
}

// ---------------- multi-block exclusive scan --------------------------------
#define SCAN_BLOCKS 256
#define SCAN_TPB    256

__global__ __launch_bounds__(SCAN_TPB) void k_scan1(const int* __restrict__ deg,
                                                    int* __restrict__ bsum, int N) {
    __shared__ int sdata[SCAN_TPB];
    int b = blockIdx.x;
    int chunk = (N + SCAN_BLOCKS - 1) / SCAN_BLOCKS;
    int start = b * chunk;
    int end = start + chunk;
    if (start > N) start = N;
    if (end > N) end = N;
    int s = 0;
    for (int i = start + threadIdx.x; i < end; i += SCAN_TPB) s += deg[i];
    sdata[threadIdx.x] = s;
    __syncthreads();
    for (int o = SCAN_TPB / 2; o; o >>= 1) {
        if (threadIdx.x < o) sdata[threadIdx.x] += sdata[threadIdx.x + o];
        __syncthreads();
    }
    if (threadIdx.x == 0) bsum[b] = sdata[0];
}

__global__ __launch_bounds__(SCAN_BLOCKS) void k_scan2(const int* __restrict__ bsum,
                                                       int* __restrict__ bbase,
                                                       int* __restrict__ off_last) {
    __shared__ int sdata[SCAN_BLOCKS];
    int t = threadIdx.x;
    sdata[t] = bsum[t];
    __syncthreads();
    for (int o = 1; o < SCAN_BLOCKS; o <<= 1) {
        int v = (t >= o) ? sdata[t - o] : 0;
        __syncthreads();
        sdata[t] += v;
        __syncthreads();
    }
    bbase[t] = (t == 0) ? 0 : sdata[t - 1];
    if (t == SCAN_BLOCKS - 1) *off_last = sdata[t];
}

__global__ __launch_bounds__(SCAN_TPB) void k_scan3(const int* __restrict__ deg,
                                                    const int* __restrict__ bbase,
                                                    int* __restrict__ off,
                                                    int* __restrict__ cur, int N) {
    __shared__ int sdata[SCAN_TPB];
    int b = blockIdx.x;
    int chunk = (N + SCAN_BLOCKS - 1) / SCAN_BLOCKS;
    int start = b * chunk;
    int end = start + chunk;
    if (start > N) start = N;
    if (end > N) end = N;
    int base = bbase[b];
    for (int i0 = start; i0 < end; i0 += SCAN_TPB) {
        int i = i0 + threadIdx.x;
        int v = (i < end) ? deg[i] : 0;
        sdata[threadIdx.x] = v;
        __syncthreads();
        for (int o = 1; o < SCAN_TPB; o <<= 1) {
            int u = (threadIdx.x >= o) ? sdata[threadIdx.x - o] : 0;
            __syncthreads();
            sdata[threadIdx.x] += u;
            __syncthreads();
        }
        if (i < end) {
            int excl = base + sdata[threadIdx.x] - v;
            off[i] = excl;
            cur[i] = excl;
        }
        base += sdata[SCAN_TPB - 1];
        __syncthreads();
    }
}

__global__ void k_fill(const void* ei, const int* flag, int E, int N, int* cur, int* csr) {
    int e = blockIdx.x * blockDim.x + threadIdx.x;
    int Etot = E + N;
    if (e >= Etot) return;
    int is32 = *flag;
    int src, dst;
    if (e < E) {
        src = edge_at(ei, is32, e);
        dst = edge_at(ei, is32, (long long)E + e);
    } else {
        src = e - E;
        dst = e - E;
    }
    int pos = atomicAdd(&cur[dst], 1);
    csr[pos] = src;
}

// ---------------- merged operand prep ---------------------------------------
// idx < Nf: xh = fp16(x). Then four weight transposes to single fp16:
// W [nblk][K][128] fp32 -> [nblk*128 cols][K] fp16.
__global__ void k_prep(const float* __restrict__ x, u16* __restrict__ xh, int Nf,
                       const float* __restrict__ encW, u16* __restrict__ eh,
                       const float* __restrict__ linW, u16* __restrict__ lh,
                       const float* __restrict__ decW, u16* __restrict__ dh,
                       const float* __restrict__ dlW, u16* __restrict__ dh2) {
    int i = blockIdx.x * blockDim.x + threadIdx.x;
    if (i < Nf) {
        xh[i] = f2h_bits(x[i]);
        return;
    }
    int j = i - Nf;
    const int WSZ = HEADS * FDIM * FDIM;
    const float* W;
    u16* hi;
    int K;
    if (j < WSZ)            { W = encW; hi = eh;  K = FDIM; }
    else if (j < 2 * WSZ)   { W = linW; hi = lh;  K = HCAT; j -= WSZ; }
    else if (j < 3 * WSZ)   { W = decW; hi = dh;  K = FDIM; j -= 2 * WSZ; }
    else if (j < 4 * WSZ)   { W = dlW;  hi = dh2; K = HCAT; j -= 3 * WSZ; }
    else return;
    int blk = j / (K * 128);
    int rem = j - blk * K * 128;
    int k = rem >> 7, col = rem & 127;
    hi[(size_t)blk * 128 * K + (size_t)col * K + k] = f2h_bits(W[j]);
}

// ---------------- fp16 MFMA GEMM (round-9 loop, single fp16 weights) --------
// MODE 0 (head GEMM): writes Hb=fp16 + fused scores ssrc/sdst[yb][row].
// MODE 1 (enc lin): bias+relu -> fp16. MODE 2 (dec lin): bias+relu -> fp32.
template <int MODE>
__global__ __launch_bounds__(256) void k_gemm_f16(
    const u16* __restrict__ A, int lda,
    const u16* __restrict__ Bt,
    const float* __restrict__ bias,
    const float* __restrict__ asrc, const float* __restrict__ adst,
    float* __restrict__ C, u16* __restrict__ Cb1,
    float* __restrict__ ssrc, float* __restrict__ sdst,
    int ldc, int M, int K)
{
    __shared__ alignas(16) char smem[16384];
    __shared__ float sred[512];
    const int ASH = 0, BHI = 8192;
    int tid = threadIdx.x;
    int bm0 = blockIdx.x * 128;
    int yb = blockIdx.y;

    int wid = tid >> 6, lane = tid & 63;
    int wr = wid >> 1, wc = wid & 1;
    int fr = lane & 15, g = lane >> 4;

    f32x4 acc[4][4] = {};

    int arow = tid >> 1, ahalf = tid & 1;
    bool ain = (bm0 + arow) < M;
    const u16* aptr = A + (size_t)(bm0 + arow) * lda + ahalf * 16;
    int bcol = tid & 127, bhalf = tid >> 7;
    const u16* bph = Bt + (size_t)yb * 128 * K + (size_t)bcol * K + bhalf * 16;

    int abase = arow * 64 + ahalf * 32;
    int asw = (arow & 7) << 4;
    int bbase = bcol * 64 + bhalf * 32;
    int bsw = (bcol & 7) << 4;

    // prologue: issue loads for tile 0
    uint4 va0, va1, vb0, vb1;
    if (ain) { va0 = *(const uint4*)(aptr); va1 = *(const uint4*)(aptr + 8); }
    else { va0 = make_uint4(0, 0, 0, 0); va1 = make_uint4(0, 0, 0, 0); }
    vb0 = *(const uint4*)(bph);
    vb1 = *(const uint4*)(bph + 8);

    for (int k0 = 0; k0 < K; k0 += 32) {
        // stage the already-loaded tile (vmcnt wait covered by prev MFMAs)
        *(uint4*)(smem + ASH + ((abase +  0) ^ asw)) = va0;
        *(uint4*)(smem + ASH + ((abase + 16) ^ asw)) = va1;
        *(uint4*)(smem + BHI + ((bbase +  0) ^ bsw)) = vb0;
        *(uint4*)(smem + BHI + ((bbase + 16) ^ bsw)) = vb1;

        __syncthreads();

        // issue next tile's loads now; consumed at next iteration's stage
        if (k0 + 32 < K) {
            int kn = k0 + 32;
            if (ain) { va0 = *(const uint4*)(aptr + kn); va1 = *(const uint4*)(aptr + kn + 8); }
            else { va0 = make_uint4(0, 0, 0, 0); va1 = make_uint4(0, 0, 0, 0); }
            vb0 = *(const uint4*)(bph + kn);
            vb1 = *(const uint4*)(bph + kn + 8);
        }

        f16x8 af[4], bh[4];
#pragma unroll
        for (int mi = 0; mi < 4; ++mi) {
            int r = wr * 64 + mi * 16 + fr;
            int off = (r * 64 + g * 16) ^ ((r & 7) << 4);
            af[mi] = *(f16x8*)(smem + ASH + off);
        }
#pragma unroll
        for (int nj = 0; nj < 4; ++nj) {
            int c = wc * 64 + nj * 16 + fr;
            int off = (c * 64 + g * 16) ^ ((c & 7) << 4);
            bh[nj] = *(f16x8*)(smem + BHI + off);
        }

#pragma unroll
        for (int mi = 0; mi < 4; ++mi)
#pragma unroll
            for (int nj = 0; nj < 4; ++nj)
                acc[mi][nj] = __builtin_amdgcn_mfma_f32_16x16x32_f16(af[mi], bh[nj], acc[mi][nj], 0, 0, 0);
        __syncthreads();
    }

    // ---- main output stores ----
#pragma unroll
    for (int mi = 0; mi < 4; ++mi) {
#pragma unroll
        for (int q = 0; q < 4; ++q) {
            int r = bm0 + wr * 64 + mi * 16 + g * 4 + q;
            if (r >= M) continue;
#pragma unroll
            for (int nj = 0; nj < 4; ++nj) {
                int c = wc * 64 + nj * 16 + fr;     // col within yb's 128
                float v = acc[mi][nj][q];
                if (MODE == 0) {
                    Cb1[(size_t)r * ldc + yb * 128 + c] = f2h_bits(v);
                } else if (MODE == 1) {
                    v += bias[c];
                    v = fmaxf(v, 0.f);
                    Cb1[(size_t)r * ldc + c] = f2h_bits(v);
                } else {
                    v += bias[c];
                    v = fmaxf(v, 0.f);
                    C[(size_t)r * ldc + c] = v;
                }
            }
        }
    }

    // ---- MODE 0: fused attention scores for head yb ----
    if (MODE == 0) {
        float asv[4], adv[4];
        const float* app = asrc + yb * FDIM;
        const float* dpp = adst + yb * FDIM;
#pragma unroll
        for (int nj = 0; nj < 4; ++nj) {
            int c = wc * 64 + nj * 16 + fr;
            asv[nj] = app[c];
            adv[nj] = dpp[c];
        }
#pragma unroll
        for (int mi = 0; mi < 4; ++mi) {
#pragma unroll
            for (int q = 0; q < 4; ++q) {
                float ps = 0.f, pd = 0.f;
#pragma unroll
                for (int nj = 0; nj < 4; ++nj) {
                    ps += acc[mi][nj][q] * asv[nj];
                    pd += acc[mi][nj][q] * adv[nj];
                }
#pragma unroll
                for (int o = 1; o < 16; o <<= 1) {
                    ps += __shfl_xor(ps, o);
                    pd += __shfl_xor(pd, o);
                }
                if (fr == 0) {
                    int row128 = wr * 64 + mi * 16 + g * 4 + q;
                    sred[(row128 * 2 + wc) * 2 + 0] = ps;
                    sred[(row128 * 2 + wc) * 2 + 1] = pd;
                }
            }
        }
        __syncthreads();
        {
            int rg = tid >> 1;          // 0..127
            int which = tid & 1;
            int r = bm0 + rg;
            if (r < M) {
                float v = sred[(rg * 2 + 0) * 2 + which] + sred[(rg * 2 + 1) * 2 + which];
                float* dstp = which ? sdst : ssrc;
                dstp[(size_t)yb * M + r] = v;
            }
        }
    }
}

// ---------------- segment softmax + fp16 gather aggregate (round-9) ---------
__global__ __launch_bounds__(64) void k_aggregate(
    const u16* __restrict__ Hb, const int* __restrict__ off,
    const int* __restrict__ csr, const float* __restrict__ ssrc,
    const float* __restrict__ sdst, const float* __restrict__ bvec,
    u16* __restrict__ Gh, int N) {
    int n = blockIdx.x;
    int lane = threadIdx.x;
    int o0 = __builtin_amdgcn_readfirstlane(off[n]);
    int o1 = __builtin_amdgcn_readfirstlane(off[n + 1]);
    int h = lane >> 4;
    int col0 = lane * 8;
    float sdh = sdst[(size_t)h * N + n];
    const float* ssrc_h = ssrc + (size_t)h * N;
    float denom = 0.f;
    float acc[8] = {0.f, 0.f, 0.f, 0.f, 0.f, 0.f, 0.f, 0.f};

    auto body = [&](float ew, uint4 hv) {
        const __half2* hp = (const __half2*)&hv;
#pragma unroll
        for (int j = 0; j < 4; ++j) {
            float2 f = __half22float2(hp[j]);
            acc[2 * j]     += ew * f.x;
            acc[2 * j + 1] += ew * f.y;
        }
    };

    int i = o0;
    for (; i + 4 <= o1; i += 4) {
        int s0 = csr[i + 0], s1 = csr[i + 1], s2 = csr[i + 2], s3 = csr[i + 3];
        uint4 v0 = *(const uint4*)&Hb[(size_t)s0 * HCAT + col0];
        uint4 v1 = *(const uint4*)&Hb[(size_t)s1 * HCAT + col0];
        uint4 v2 = *(const uint4*)&Hb[(size_t)s2 * HCAT + col0];
        uint4 v3 = *(const uint4*)&Hb[(size_t)s3 * HCAT + col0];
        float e0 = ssrc_h[s0] + sdh, e1 = ssrc_h[s1] + sdh;
        float e2 = ssrc_h[s2] + sdh, e3 = ssrc_h[s3] + sdh;
        e0 = e0 >= 0.f ? e0 : 0.2f * e0;
        e1 = e1 >= 0.f ? e1 : 0.2f * e1;
        e2 = e2 >= 0.f ? e2 : 0.2f * e2;
        e3 = e3 >= 0.f ? e3 : 0.2f * e3;
        float w0 = __expf(e0), w1 = __expf(e1), w2 = __expf(e2), w3 = __expf(e3);
        denom += (w0 + w1) + (w2 + w3);
        body(w0, v0);
        body(w1, v1);
        body(w2, v2);
        body(w3, v3);
    }
    for (; i < o1; ++i) {
        int s = csr[i];
        uint4 v = *(const uint4*)&Hb[(size_t)s * HCAT + col0];
        float e = ssrc_h[s] + sdh;
        e = e >= 0.f ? e : 0.2f * e;
        float ew = __expf(e);
        denom += ew;
        body(ew, v);
    }

    float inv = 1.f / denom;
    u16 hs[8];
#pragma unroll
    for (int k = 0; k < 8; ++k) {
        int col = col0 + k;
        float v = acc[k] * inv + bvec[h * FDIM + (col & 127)];
        hs[k] = f2h_bits(v);
    }
    *(uint4*)&Gh[(size_t)n * HCAT + col0] = *(uint4*)hs;
}

// ---------------------------------------------------------------------------
extern "C" void kernel_launch(void* const* d_in, const int* in_sizes, int n_in,
                              void* d_out, int out_size, void* d_ws, size_t ws_size,
                              hipStream_t stream) {
    const float* x = (const float*)d_in[0];
    const void* ei = d_in[1];
    const float* encW = (const float*)d_in[2];
    const float* enc_asrc = (const float*)d_in[3];
    const float* enc_adst = (const float*)d_in[4];
    const float* enc_b = (const float*)d_in[5];
    const float* enc_linW = (const float*)d_in[6];
    const float* enc_linb = (const float*)d_in[7];
    const float* decW = (const float*)d_in[8];
    const float* dec_asrc = (const float*)d_in[9];
    const float* dec_adst = (const float*)d_in[10];
    const float* dec_b = (const float*)d_in[11];
    const float* dec_linW = (const float*)d_in[12];
    const float* dec_linb = (const float*)d_in[13];

    int N = in_sizes[0] / FDIM;
    int E = in_sizes[1] / 2;
    int Etot = E + N;

    char* w = (char*)d_ws;
    size_t o = 0;
    auto alloc = [&](size_t bytes) -> char* {
        char* p = w + o;
        o += (bytes + 255) & ~(size_t)255;
        return p;
    };
    int* flag = (int*)alloc(4);
    int* deg = (int*)alloc((size_t)N * 4);
    int* off = (int*)alloc((size_t)(N + 1) * 4);
    int* cur = (int*)alloc((size_t)N * 4);
    int* csr = (int*)alloc((size_t)Etot * 4);
    int* bsum = (int*)alloc(SCAN_BLOCKS * 4);
    int* bbase = (int*)alloc(SCAN_BLOCKS * 4);
    float* ssrc = (float*)alloc((size_t)HEADS * N * 4);
    float* sdst = (float*)alloc((size_t)HEADS * N * 4);
    u16* Gh = (u16*)alloc((size_t)N * HCAT * 2);
    u16* Hb = (u16*)alloc((size_t)N * HCAT * 2);
    u16* xh = (u16*)alloc((size_t)N * FDIM * 2);
    u16* X2h = (u16*)alloc((size_t)N * FDIM * 2);
    u16* encWt_h = (u16*)alloc((size_t)HEADS * FDIM * FDIM * 2);
    u16* linWt_h = (u16*)alloc((size_t)HCAT * FDIM * 2);
    u16* decWt_h = (u16*)alloc((size_t)HEADS * FDIM * FDIM * 2);
    u16* dlinWt_h = (u16*)alloc((size_t)HCAT * FDIM * 2);
    (void)ws_size;

    // CSR build
    k_detect_zero<<<(N + 255) / 256, 256, 0, stream>>>(ei, E, N, flag, deg);
    k_count<<<(Etot + 255) / 256, 256, 0, stream>>>(ei, flag, E, N, deg);
    k_scan1<<<SCAN_BLOCKS, SCAN_TPB, 0, stream>>>(deg, bsum, N);
    k_scan2<<<1, SCAN_BLOCKS, 0, stream>>>(bsum, bbase, off + N);
    k_scan3<<<SCAN_BLOCKS, SCAN_TPB, 0, stream>>>(deg, bbase, off, cur, N);
    k_fill<<<(Etot + 255) / 256, 256, 0, stream>>>(ei, flag, E, N, cur, csr);

    // merged operand prep (xh + 4 weight transposes)
    int Nf = N * FDIM;
    int prep_total = Nf + 4 * HEADS * FDIM * FDIM;
    k_prep<<<(prep_total + 255) / 256, 256, 0, stream>>>(
        x, xh, Nf,
        encW, encWt_h,
        enc_linW, linWt_h,
        decW, decWt_h,
        dec_linW, dlinWt_h);

    int mblocks = (N + 127) / 128;

    // ---- encoder ----
    k_gemm_f16<0><<<dim3(mblocks, 4), 256, 0, stream>>>(
        xh, FDIM, encWt_h, nullptr, enc_asrc, enc_adst,
        nullptr, Hb, ssrc, sdst, HCAT, N, FDIM);
    k_aggregate<<<N, 64, 0, stream>>>(Hb, off, csr, ssrc, sdst, enc_b, Gh, N);
    k_gemm_f16<1><<<dim3(mblocks, 1), 256, 0, stream>>>(
        Gh, HCAT, linWt_h, enc_linb, nullptr, nullptr,
        nullptr, X2h, nullptr, nullptr, FDIM, N, HCAT);

    // ---- decoder ----
    k_gemm_f16<0><<<dim3(mblocks, 4), 256, 0, stream>>>(
        X2h, FDIM, decWt_h, nullptr, dec_asrc, dec_adst,
        nullptr, Hb, ssrc, sdst, HCAT, N, FDIM);
    k_aggregate<<<N, 64, 0, stream>>>(Hb, off, csr, ssrc, sdst, dec_b, Gh, N);
    k_gemm_f16<2><<<dim3(mblocks, 1), 256, 0, stream>>>(
        Gh, HCAT, dlinWt_h, dec_linb, nullptr, nullptr,
        (float*)d_out, nullptr, nullptr, nullptr, FDIM, N, HCAT);
}